// Round 6
// baseline (1106.422 us; speedup 1.0000x reference)
//
#include <hip/hip_runtime.h>

typedef unsigned short ushort_t;
typedef unsigned int uint_t;
typedef short short8 __attribute__((ext_vector_type(8)));
typedef _Float16 half8 __attribute__((ext_vector_type(8)));
typedef float f32x4 __attribute__((ext_vector_type(4)));
typedef uint_t u32x2 __attribute__((ext_vector_type(2)));

__device__ __forceinline__ float sigm(float x) { return 1.f / (1.f + __expf(-x)); }
__device__ __forceinline__ float tanh_s(float x) {
  float e = __expf(2.f * fabsf(x));
  float r = 1.f - 2.f / (e + 1.f);
  return copysignf(r, x);
}
__device__ __forceinline__ uint_t cvtpk_bf16(float a, float b) {
  uint_t r;
  asm("v_cvt_pk_bf16_f32 %0, %1, %2" : "=v"(r) : "v"(a), "v"(b));
  return r;
}
__device__ __forceinline__ short8 ld_cvt8(const float* p) {
  f32x4 v0 = *(const f32x4*)p;
  f32x4 v1 = *(const f32x4*)(p + 4);
  union { short8 s; uint_t u[4]; } r;
  r.u[0] = cvtpk_bf16(v0[0], v0[1]);
  r.u[1] = cvtpk_bf16(v0[2], v0[3]);
  r.u[2] = cvtpk_bf16(v1[0], v1[1]);
  r.u[3] = cvtpk_bf16(v1[2], v1[3]);
  return r.s;
}
__device__ __forceinline__ float f16b2f(uint_t bits) {
  union { ushort_t s; _Float16 h; } v; v.s = (ushort_t)bits; return (float)v.h;
}
__device__ __forceinline__ uint_t f2f16b(float f) {
  union { _Float16 h; ushort_t s; } v; v.h = (_Float16)f; return v.s;
}

#define MFMAB(a, b, c) __builtin_amdgcn_mfma_f32_16x16x32_bf16((a), (b), (c), 0, 0, 0)
#define MFMAH(a, b, c) __builtin_amdgcn_mfma_f32_16x16x32_f16((a), (b), (c), 0, 0, 0)

// =====================================================================
// Kernel 1: fully-fused gate GEMM.  Block = 8 waves; wave wv owns hidden
// cols jj=wv*16..+15 for ALL 8 weight panels (B-frags in VGPRs, no LDS).
// G cell (8 bytes, u32x2): lo = {f16 g0+b0, f16 g3+b3}
//                          hi = {f16 g4+b4+gt2, u8 T1, u8 T2}
//   T1 = sigm(gx1+b1+tanh(td@min(Wt0,0))), T2 = sigm(gx2+b2+tanh(td@Wt1))
// G layout: [m = batch*TC+tt][col 0..127] of u32x2.
// =====================================================================
__global__ __launch_bounds__(512) void gemm_g(
    const float* __restrict__ x, const float* __restrict__ td,
    const float* __restrict__ wx, const float* __restrict__ wt,
    const float* __restrict__ bias, u32x2* __restrict__ G,
    int t0, int TC, int ltc, int rpt)
{
  const int tid = threadIdx.x;
  const int wv = tid >> 6, lane = tid & 63;
  const int l15 = lane & 15, lg = lane >> 4;
  const int jj = wv * 16 + l15;

  // ---- B-fragments: Wx segs 0..4, Wt segs 0..2 (K=64 -> 2 frags each) ----
  short8 Bx[5][2], Bt[3][2];
#pragma unroll
  for (int s = 0; s < 5; ++s)
#pragma unroll
    for (int f = 0; f < 2; ++f) {
      const float* wp = wx + (size_t)(f * 32 + lg * 8) * 640 + s * 128 + jj;
      union { short8 v; uint_t u[4]; } r;
#pragma unroll
      for (int q = 0; q < 4; ++q)
        r.u[q] = cvtpk_bf16(wp[(2 * q) * 640], wp[(2 * q + 1) * 640]);
      Bx[s][f] = r.v;
    }
#pragma unroll
  for (int s = 0; s < 3; ++s)
#pragma unroll
    for (int f = 0; f < 2; ++f) {
      const float* wp = wt + (size_t)(f * 32 + lg * 8) * 384 + s * 128 + jj;
      union { short8 v; uint_t u[4]; } r;
#pragma unroll
      for (int q = 0; q < 4; ++q) {
        float w0 = wp[(2 * q) * 384], w1 = wp[(2 * q + 1) * 384];
        if (s == 0) { w0 = fminf(w0, 0.f); w1 = fminf(w1, 0.f); }
        r.u[q] = cvtpk_bf16(w0, w1);
      }
      Bt[s][f] = r.v;
    }

  const float b0f = bias[jj], b1f = bias[128 + jj], b2f = bias[256 + jj];
  const float b3f = bias[384 + jj], b4f = bias[512 + jj];

#pragma unroll 1
  for (int it = 0; it < rpt; ++it) {
    const int m0 = (blockIdx.x * rpt + it) * 16;
    const int m = m0 + l15;
    const int bb = m >> ltc, tt = m & (TC - 1);
    const size_t ro = ((size_t)(bb * 512) + t0 + tt) * 64 + lg * 8;
    short8 xa0 = ld_cvt8(x + ro), xa1 = ld_cvt8(x + ro + 32);
    short8 ta0 = ld_cvt8(td + ro), ta1 = ld_cvt8(td + ro + 32);

    f32x4 g0{}, g1{}, g2{}, g3{}, g4{}, q0{}, q1{}, q2{};
    g0 = MFMAB(xa0, Bx[0][0], g0); g0 = MFMAB(xa1, Bx[0][1], g0);
    g1 = MFMAB(xa0, Bx[1][0], g1); g1 = MFMAB(xa1, Bx[1][1], g1);
    g2 = MFMAB(xa0, Bx[2][0], g2); g2 = MFMAB(xa1, Bx[2][1], g2);
    g3 = MFMAB(xa0, Bx[3][0], g3); g3 = MFMAB(xa1, Bx[3][1], g3);
    g4 = MFMAB(xa0, Bx[4][0], g4); g4 = MFMAB(xa1, Bx[4][1], g4);
    q0 = MFMAB(ta0, Bt[0][0], q0); q0 = MFMAB(ta1, Bt[0][1], q0);
    q1 = MFMAB(ta0, Bt[1][0], q1); q1 = MFMAB(ta1, Bt[1][1], q1);
    q2 = MFMAB(ta0, Bt[2][0], q2); q2 = MFMAB(ta1, Bt[2][1], q2);

#pragma unroll
    for (int r = 0; r < 4; ++r) {
      float v0 = g0[r] + b0f;
      float T1 = sigm(g1[r] + b1f + tanh_s(q0[r]));
      float T2 = sigm(g2[r] + b2f + tanh_s(q1[r]));
      float v3 = g3[r] + b3f;
      float v4 = g4[r] + b4f + q2[r];
      uint_t t1u = (uint_t)(T1 * 255.f + 0.5f);
      uint_t t2u = (uint_t)(T2 * 255.f + 0.5f);
      u32x2 P;
      P[0] = f2f16b(v0) | (f2f16b(v3) << 16);
      P[1] = f2f16b(v4) | (t1u << 16) | (t2u << 24);
      G[(size_t)(m0 + lg * 4 + r) * 128 + jj] = P;
    }
  }
}

// =====================================================================
// Kernel 2: MFMA serial scan (f16).  Block = 4 REAL batch rows, 8 waves.
// A-tile rows 4..15 held at zero (their D rows are exactly 0 -> inert).
// Wave wv owns hidden cols jj for all 3 Wh segments (f16 B-frags, 48 VGPR).
// Per step: 4 ds_read_b128 (h, XOR-swizzled dbuf LDS) -> 12 MFMA ->
// xh in-lane -> gates on lg==0 lanes (c in regs) -> ONE barrier.
// G prefetched 2 steps ahead in registers.
// =====================================================================
__global__ __launch_bounds__(512) void scan_k(
    const u32x2* __restrict__ G, const float* __restrict__ wh,
    float* __restrict__ out, float* __restrict__ sh, float* __restrict__ sc,
    int t0, int t1, int TC)
{
  __shared__ __attribute__((aligned(16))) char h_lds[2][4096];
  const int tid = threadIdx.x;
  const int wv = tid >> 6, lane = tid & 63;
  const int l15 = lane & 15, lg = lane >> 4;
  const int jj = wv * 16 + l15;
  const int b0 = blockIdx.x * 4;

  // ---- Wh B-fragments (f16): segs 0..2, K=128 -> 4 frags each ----
  half8 Bf[3][4];
#pragma unroll
  for (int s = 0; s < 3; ++s)
#pragma unroll
    for (int f = 0; f < 4; ++f) {
      const float* wp = wh + (size_t)(f * 32 + lg * 8) * 384 + s * 128 + jj;
      half8 r;
#pragma unroll
      for (int q = 0; q < 8; ++q) r[q] = (_Float16)wp[q * 384];
      Bf[s][f] = r;
    }

  // ---- zero both h buffers, then write real rows 0..3 ----
  for (int e = tid; e < 2048; e += 512) {
    ((uint_t*)h_lds[0])[e] = 0;
    ((uint_t*)h_lds[1])[e] = 0;
  }
  __syncthreads();

  const bool own = (lg == 0);
  float c_st[4], h_st[4];
  const u32x2* Gp[4];
#pragma unroll
  for (int r = 0; r < 4; ++r) {
    float hv = 0.f, cv = 0.f;
    if (own && t0 > 0) { hv = sh[(b0 + r) * 128 + jj]; cv = sc[(b0 + r) * 128 + jj]; }
    h_st[r] = hv; c_st[r] = cv;
    Gp[r] = G + (own ? ((size_t)(b0 + r) * TC) * 128 + jj : (size_t)jj);
    if (own)
      *(_Float16*)(h_lds[0] + r * 256 + ((jj * 2) ^ (r << 4))) = (_Float16)hv;
  }
  u32x2 GA[4], GB[4];
#pragma unroll
  for (int r = 0; r < 4; ++r) { GA[r] = Gp[r][0]; GB[r] = Gp[r][128]; }
  __syncthreads();

#define STEP(GC, TT, CUR, NXT)                                                 \
  {                                                                            \
    u32x2 cur[4];                                                              \
    int tp = (TT) + 2; if (tp > TC - 1) tp = TC - 1;                           \
    _Pragma("unroll")                                                          \
    for (int r = 0; r < 4; ++r) {                                              \
      cur[r] = GC[r];                                                          \
      GC[r] = Gp[r][(size_t)tp * 128];                                         \
    }                                                                          \
    const char* hb = h_lds[CUR];                                               \
    const int sw = (l15 & 7) << 4;                                             \
    half8 a0 = *(const half8*)(hb + l15 * 256 + ((0   + lg * 16) ^ sw));       \
    half8 a1 = *(const half8*)(hb + l15 * 256 + ((64  + lg * 16) ^ sw));       \
    half8 a2 = *(const half8*)(hb + l15 * 256 + ((128 + lg * 16) ^ sw));       \
    half8 a3 = *(const half8*)(hb + l15 * 256 + ((192 + lg * 16) ^ sw));       \
    f32x4 x0{}, x1{}, x2{};                                                    \
    x0 = MFMAH(a0, Bf[0][0], x0); x0 = MFMAH(a1, Bf[0][1], x0);                \
    x0 = MFMAH(a2, Bf[0][2], x0); x0 = MFMAH(a3, Bf[0][3], x0);                \
    x1 = MFMAH(a0, Bf[1][0], x1); x1 = MFMAH(a1, Bf[1][1], x1);                \
    x1 = MFMAH(a2, Bf[1][2], x1); x1 = MFMAH(a3, Bf[1][3], x1);                \
    x2 = MFMAH(a0, Bf[2][0], x2); x2 = MFMAH(a1, Bf[2][1], x2);                \
    x2 = MFMAH(a2, Bf[2][2], x2); x2 = MFMAH(a3, Bf[2][3], x2);                \
    if (own) {                                                                 \
      _Pragma("unroll")                                                        \
      for (int r = 0; r < 4; ++r) {                                            \
        uint_t lo = cur[r][0], hi = cur[r][1];                                 \
        float g0v = f16b2f(lo & 0xffffu), g3v = f16b2f(lo >> 16);              \
        float g4v = f16b2f(hi & 0xffffu);                                      \
        float T1 = (float)((hi >> 16) & 255u) * (1.f / 255.f);                 \
        float T2 = (float)(hi >> 24) * (1.f / 255.f);                          \
        float i_t = sigm(g0v + x0[r]);                                         \
        float it1 = i_t * T1;                                                  \
        float cwa = tanh_s(g3v + x1[r]);                                       \
        float ctl = sigm((1.f - it1) * c_st[r] + it1 * cwa);                   \
        float cnw = sigm((1.f - i_t) * c_st[r] + i_t * T2 * cwa);              \
        float o_t = sigm(g4v + x2[r]);                                         \
        float hn = o_t + tanh_s(ctl);                                          \
        c_st[r] = cnw; h_st[r] = hn;                                           \
        out[((size_t)(b0 + r) * 512 + t0 + (TT)) * 128 + jj] = hn;             \
        *(_Float16*)(h_lds[NXT] + r * 256 + ((jj * 2) ^ (r << 4))) =           \
            (_Float16)hn;                                                      \
      }                                                                        \
    }                                                                          \
    asm volatile("s_waitcnt lgkmcnt(0)" ::: "memory");                         \
    __builtin_amdgcn_s_barrier();                                              \
    __builtin_amdgcn_sched_barrier(0);                                         \
  }

  for (int tt = 0; tt < TC; tt += 2) {
    STEP(GA, tt, 0, 1);
    STEP(GB, tt + 1, 1, 0);
  }
#undef STEP

  if (own) {
#pragma unroll
    for (int r = 0; r < 4; ++r) {
      if (t1 == 512) {
        out[(size_t)16777216 + (b0 + r) * 128 + jj] = h_st[r];          // h_f
        out[(size_t)16777216 + 32768 + (b0 + r) * 128 + jj] = c_st[r];  // c_f
      } else {
        sh[(b0 + r) * 128 + jj] = h_st[r];
        sc[(b0 + r) * 128 + jj] = c_st[r];
      }
    }
  }
}

// =====================================================================
extern "C" void kernel_launch(void* const* d_in, const int* in_sizes, int n_in,
                              void* d_out, int out_size, void* d_ws, size_t ws_size,
                              hipStream_t stream) {
  const float* x    = (const float*)d_in[0];
  const float* td   = (const float*)d_in[1];
  const float* wx   = (const float*)d_in[2];
  const float* wh   = (const float*)d_in[3];
  const float* wt   = (const float*)d_in[4];
  const float* bias = (const float*)d_in[5];
  float* out = (float*)d_out;

  // G: 256*TC rows * 128 cols * 8 B   (TC=512 -> 134 MB; ws proven >= 201 MB)
  int TC = 512;
  while (TC > 16 && (size_t)256 * TC * 128 * 8 + 262144 > ws_size) TC >>= 1;
  int ltc = 0; while ((1 << ltc) < TC) ++ltc;

  u32x2* G = (u32x2*)d_ws;
  float* sh = (float*)((char*)d_ws + (size_t)256 * TC * 128 * 8);
  float* sc = sh + 256 * 128;

  const int rpt = 16;                         // 16-row tiles per gemm block
  const int gblocks = (256 * TC / 16) / rpt;  // = TC at rpt=16

  for (int t0 = 0; t0 < 512; t0 += TC) {
    gemm_g<<<gblocks, 512, 0, stream>>>(x, td, wx, wt, bias, G, t0, TC, ltc, rpt);
    scan_k<<<64, 512, 0, stream>>>(G, wh, out, sh, sc, t0, t0 + TC, TC);
  }
}

// Round 7
// 449.675 us; speedup vs baseline: 2.4605x; 2.4605x over previous
//
#include <hip/hip_runtime.h>

typedef unsigned short ushort_t;
typedef unsigned int uint_t;
typedef short short8 __attribute__((ext_vector_type(8)));
typedef float f32x4 __attribute__((ext_vector_type(4)));
typedef uint_t u32x2 __attribute__((ext_vector_type(2)));
typedef _Float16 half2_t __attribute__((ext_vector_type(2)));

__device__ __forceinline__ float sigm(float x) { return 1.f / (1.f + __expf(-x)); }
__device__ __forceinline__ float tanh_s(float x) {
  float e = __expf(2.f * fabsf(x));
  float r = 1.f - 2.f / (e + 1.f);
  return copysignf(r, x);
}
__device__ __forceinline__ float dot2h(half2_t a, half2_t b, float c) {
#if __has_builtin(__builtin_amdgcn_fdot2)
  return __builtin_amdgcn_fdot2(a, b, c, false);
#else
  return c + (float)a.x * (float)b.x + (float)a.y * (float)b.y;
#endif
}
__device__ __forceinline__ uint_t cvtpk_bf16(float a, float b) {
  uint_t r;
  asm("v_cvt_pk_bf16_f32 %0, %1, %2" : "=v"(r) : "v"(a), "v"(b));
  return r;
}
__device__ __forceinline__ short8 ld_cvt8(const float* p) {
  f32x4 v0 = *(const f32x4*)p;
  f32x4 v1 = *(const f32x4*)(p + 4);
  union { short8 s; uint_t u[4]; } r;
  r.u[0] = cvtpk_bf16(v0[0], v0[1]);
  r.u[1] = cvtpk_bf16(v0[2], v0[3]);
  r.u[2] = cvtpk_bf16(v1[0], v1[1]);
  r.u[3] = cvtpk_bf16(v1[2], v1[3]);
  return r.s;
}
__device__ __forceinline__ float f16b2f(uint_t bits) {
  union { ushort_t s; _Float16 h; } v; v.s = (ushort_t)bits; return (float)v.h;
}
__device__ __forceinline__ uint_t f2f16b(float f) {
  union { _Float16 h; ushort_t s; } v; v.h = (_Float16)f; return v.s;
}

#define MFMAB(a, b, c) __builtin_amdgcn_mfma_f32_16x16x32_bf16((a), (b), (c), 0, 0, 0)

// =====================================================================
// Kernel 1 (unchanged from round 6, measured ~88 us, PASS):
// fully-fused gate GEMM.  Block = 8 waves; wave wv owns hidden cols
// jj=wv*16..+15 for ALL 8 weight panels (B-frags in VGPRs, no LDS).
// G cell (8 bytes, u32x2): lo = {f16 g0+b0, f16 g3+b3}
//                          hi = {f16 g4+b4+gt2, u8 T1, u8 T2}
//   T1 = sigm(gx1+b1+tanh(td@min(Wt0,0))), T2 = sigm(gx2+b2+tanh(td@Wt1))
// G layout: [m = batch*TC+tt][col 0..127] of u32x2.
// =====================================================================
__global__ __launch_bounds__(512) void gemm_g(
    const float* __restrict__ x, const float* __restrict__ td,
    const float* __restrict__ wx, const float* __restrict__ wt,
    const float* __restrict__ bias, u32x2* __restrict__ G,
    int t0, int TC, int ltc, int rpt)
{
  const int tid = threadIdx.x;
  const int wv = tid >> 6, lane = tid & 63;
  const int l15 = lane & 15, lg = lane >> 4;
  const int jj = wv * 16 + l15;

  short8 Bx[5][2], Bt[3][2];
#pragma unroll
  for (int s = 0; s < 5; ++s)
#pragma unroll
    for (int f = 0; f < 2; ++f) {
      const float* wp = wx + (size_t)(f * 32 + lg * 8) * 640 + s * 128 + jj;
      union { short8 v; uint_t u[4]; } r;
#pragma unroll
      for (int q = 0; q < 4; ++q)
        r.u[q] = cvtpk_bf16(wp[(2 * q) * 640], wp[(2 * q + 1) * 640]);
      Bx[s][f] = r.v;
    }
#pragma unroll
  for (int s = 0; s < 3; ++s)
#pragma unroll
    for (int f = 0; f < 2; ++f) {
      const float* wp = wt + (size_t)(f * 32 + lg * 8) * 384 + s * 128 + jj;
      union { short8 v; uint_t u[4]; } r;
#pragma unroll
      for (int q = 0; q < 4; ++q) {
        float w0 = wp[(2 * q) * 384], w1 = wp[(2 * q + 1) * 384];
        if (s == 0) { w0 = fminf(w0, 0.f); w1 = fminf(w1, 0.f); }
        r.u[q] = cvtpk_bf16(w0, w1);
      }
      Bt[s][f] = r.v;
    }

  const float b0f = bias[jj], b1f = bias[128 + jj], b2f = bias[256 + jj];
  const float b3f = bias[384 + jj], b4f = bias[512 + jj];

#pragma unroll 1
  for (int it = 0; it < rpt; ++it) {
    const int m0 = (blockIdx.x * rpt + it) * 16;
    const int m = m0 + l15;
    const int bb = m >> ltc, tt = m & (TC - 1);
    const size_t ro = ((size_t)(bb * 512) + t0 + tt) * 64 + lg * 8;
    short8 xa0 = ld_cvt8(x + ro), xa1 = ld_cvt8(x + ro + 32);
    short8 ta0 = ld_cvt8(td + ro), ta1 = ld_cvt8(td + ro + 32);

    f32x4 g0{}, g1{}, g2{}, g3{}, g4{}, q0{}, q1{}, q2{};
    g0 = MFMAB(xa0, Bx[0][0], g0); g0 = MFMAB(xa1, Bx[0][1], g0);
    g1 = MFMAB(xa0, Bx[1][0], g1); g1 = MFMAB(xa1, Bx[1][1], g1);
    g2 = MFMAB(xa0, Bx[2][0], g2); g2 = MFMAB(xa1, Bx[2][1], g2);
    g3 = MFMAB(xa0, Bx[3][0], g3); g3 = MFMAB(xa1, Bx[3][1], g3);
    g4 = MFMAB(xa0, Bx[4][0], g4); g4 = MFMAB(xa1, Bx[4][1], g4);
    q0 = MFMAB(ta0, Bt[0][0], q0); q0 = MFMAB(ta1, Bt[0][1], q0);
    q1 = MFMAB(ta0, Bt[1][0], q1); q1 = MFMAB(ta1, Bt[1][1], q1);
    q2 = MFMAB(ta0, Bt[2][0], q2); q2 = MFMAB(ta1, Bt[2][1], q2);

#pragma unroll
    for (int r = 0; r < 4; ++r) {
      float v0 = g0[r] + b0f;
      float T1 = sigm(g1[r] + b1f + tanh_s(q0[r]));
      float T2 = sigm(g2[r] + b2f + tanh_s(q1[r]));
      float v3 = g3[r] + b3f;
      float v4 = g4[r] + b4f + q2[r];
      uint_t t1u = (uint_t)(T1 * 255.f + 0.5f);
      uint_t t2u = (uint_t)(T2 * 255.f + 0.5f);
      u32x2 P;
      P[0] = f2f16b(v0) | (f2f16b(v3) << 16);
      P[1] = f2f16b(v4) | (t1u << 16) | (t2u << 24);
      G[(size_t)(m0 + lg * 4 + r) * 128 + jj] = P;
    }
  }
}

// =====================================================================
// Kernel 2: serial scan (round-4 structure + 8B G cells).
// 1 block = 1 batch row, 768 threads, k-split-2 dot2 phase; dense gate
// phase on threads 0..127; raw s_barrier (never drains vmcnt);
// depth-4 register prefetch of G issued at the top of each step.
// =====================================================================
__global__ __launch_bounds__(768) void scan_k(
    const u32x2* __restrict__ G, const float* __restrict__ wh,
    float* __restrict__ out, float* __restrict__ sh, float* __restrict__ sc,
    int t0, int t1, int TC)
{
  __shared__ __attribute__((aligned(16))) _Float16 h_lds[128];
  __shared__ float xh_lds[768];
  const int tid = threadIdx.x;
  const int b = blockIdx.x;
  const int half = (tid >= 384) ? 1 : 0;
  const int j = tid - half * 384;

  // Wh[half*64 + 2k .. +1][j] as f16 pairs (32 VGPRs)
  half2_t w2[32];
  {
    const float* wp = wh + (size_t)(half * 64) * 384 + j;
#pragma unroll
    for (int k = 0; k < 32; ++k)
      w2[k] = half2_t{(_Float16)wp[(2 * k) * 384], (_Float16)wp[(2 * k + 1) * 384]};
  }

  float c_last = 0.f, h0v = 0.f;
  if (tid < 128) {
    if (t0 > 0) { h0v = sh[b * 128 + tid]; c_last = sc[b * 128 + tid]; }
    h_lds[tid] = (_Float16)h0v;
  }
  float h_last = h0v;

  const u32x2* Gp = G + (size_t)b * TC * 128 + (tid & 127);
  float* outp = out + (size_t)b * 65536 + tid;

  u32x2 p0{}, p1{}, p2{}, p3{};
  if (tid < 128) {
    p0 = Gp[0];
    p1 = Gp[128];
    p2 = Gp[256];
    p3 = Gp[384];
  }
  __syncthreads();

#define SCAN_STEP(P, TABS)                                                   \
  {                                                                          \
    /* issue next prefetch first: latency hides under dot+barrier+gates */   \
    u32x2 cur = P;                                                           \
    if (tid < 128) {                                                         \
      int ldr = (TABS) - t0 + 4; if (ldr > TC - 1) ldr = TC - 1;             \
      P = Gp[(size_t)ldr * 128];                                             \
    }                                                                        \
    float a0 = 0.f, a1 = 0.f, a2 = 0.f, a3 = 0.f;                            \
    const short8* hv8 = ((const short8*)h_lds) + half * 8;                   \
    _Pragma("unroll")                                                        \
    for (int kk = 0; kk < 8; ++kk) {                                         \
      union { short8 s; half2_t h[4]; } u; u.s = hv8[kk];                    \
      a0 = dot2h(u.h[0], w2[kk * 4 + 0], a0);                                \
      a1 = dot2h(u.h[1], w2[kk * 4 + 1], a1);                                \
      a2 = dot2h(u.h[2], w2[kk * 4 + 2], a2);                                \
      a3 = dot2h(u.h[3], w2[kk * 4 + 3], a3);                                \
    }                                                                        \
    xh_lds[tid] = (a0 + a1) + (a2 + a3);                                     \
    asm volatile("s_waitcnt lgkmcnt(0)" ::: "memory");                       \
    __builtin_amdgcn_s_barrier();                                            \
    if (tid < 128) {                                                         \
      float xh0 = xh_lds[tid] + xh_lds[tid + 384];                           \
      float xh1 = xh_lds[tid + 128] + xh_lds[tid + 512];                     \
      float xh2 = xh_lds[tid + 256] + xh_lds[tid + 640];                     \
      uint_t lo = cur[0], hi = cur[1];                                       \
      float g0v = f16b2f(lo & 0xffffu), g3v = f16b2f(lo >> 16);              \
      float g4v = f16b2f(hi & 0xffffu);                                      \
      float T1 = (float)((hi >> 16) & 255u) * (1.f / 255.f);                 \
      float T2 = (float)(hi >> 24) * (1.f / 255.f);                          \
      float i_t = sigm(g0v + xh0);                                           \
      float it1 = i_t * T1;                                                  \
      float cwa = tanh_s(g3v + xh1);                                         \
      float ctl = sigm((1.f - it1) * c_last + it1 * cwa);                    \
      float cnw = sigm((1.f - i_t) * c_last + i_t * T2 * cwa);               \
      float o_t = sigm(g4v + xh2);                                           \
      float hn = o_t + tanh_s(ctl);                                          \
      outp[(size_t)(TABS) * 128] = hn;                                       \
      h_lds[tid] = (_Float16)hn;                                             \
      c_last = cnw; h_last = hn;                                             \
    }                                                                        \
    asm volatile("s_waitcnt lgkmcnt(0)" ::: "memory");                       \
    __builtin_amdgcn_s_barrier();                                            \
  }

  for (int t = t0; t < t1; t += 4) {
    SCAN_STEP(p0, t);
    SCAN_STEP(p1, t + 1);
    SCAN_STEP(p2, t + 2);
    SCAN_STEP(p3, t + 3);
  }
#undef SCAN_STEP

  if (tid < 128) {
    if (t1 == 512) {
      out[(size_t)16777216 + b * 128 + tid] = h_last;            // h_f
      out[(size_t)16777216 + 32768 + b * 128 + tid] = c_last;    // c_f
    } else {
      sh[b * 128 + tid] = h_last;
      sc[b * 128 + tid] = c_last;
    }
  }
}

// =====================================================================
extern "C" void kernel_launch(void* const* d_in, const int* in_sizes, int n_in,
                              void* d_out, int out_size, void* d_ws, size_t ws_size,
                              hipStream_t stream) {
  const float* x    = (const float*)d_in[0];
  const float* td   = (const float*)d_in[1];
  const float* wx   = (const float*)d_in[2];
  const float* wh   = (const float*)d_in[3];
  const float* wt   = (const float*)d_in[4];
  const float* bias = (const float*)d_in[5];
  float* out = (float*)d_out;

  // G: 256*TC rows * 128 cols * 8 B (TC=512 -> 134 MB; proven to fit ws)
  int TC = 512;
  while (TC > 16 && (size_t)256 * TC * 128 * 8 + 262144 > ws_size) TC >>= 1;
  int ltc = 0; while ((1 << ltc) < TC) ++ltc;

  u32x2* G = (u32x2*)d_ws;
  float* sh = (float*)((char*)d_ws + (size_t)256 * TC * 128 * 8);
  float* sc = sh + 256 * 128;

  const int rpt = 16;                         // 16-row tiles per gemm block
  const int gblocks = (256 * TC / 16) / rpt;

  for (int t0 = 0; t0 < 512; t0 += TC) {
    gemm_g<<<gblocks, 512, 0, stream>>>(x, td, wx, wt, bias, G, t0, TC, ltc, rpt);
    scan_k<<<256, 768, 0, stream>>>(G, wh, out, sh, sc, t0, t0 + TC, TC);
  }
}